// Round 15
// baseline (1272.143 us; speedup 1.0000x reference)
//
#include <hip/hip_runtime.h>
#include <hip/hip_bf16.h>
#include <cmath>

typedef float  f32x4_t  __attribute__((ext_vector_type(4)));
typedef short  bf16x8_t __attribute__((ext_vector_type(8)));

__device__ __forceinline__ unsigned short f2b(float f) {
    __hip_bfloat16 h = __float2bfloat16(f);
    unsigned short r;
    __builtin_memcpy(&r, &h, 2);
    return r;
}
__device__ __forceinline__ unsigned int pk2(float lo, float hi) {
    __hip_bfloat162 h = __float22bfloat162_rn(float2{lo, hi});
    unsigned int r;
    __builtin_memcpy(&r, &h, 4);
    return r;
}
__device__ __forceinline__ void ub2(unsigned int u, float& lo, float& hi) {
    lo = __builtin_bit_cast(float, u << 16);
    hi = __builtin_bit_cast(float, u & 0xffff0000u);
}
__device__ __forceinline__ f32x4_t mfma16(bf16x8_t a, bf16x8_t b, f32x4_t c) {
    return __builtin_amdgcn_mfma_f32_16x16x32_bf16(a, b, c, 0, 0, 0);
}
__device__ __forceinline__ float gelu_f(float x) {   // NaN-safe tanh-gelu
    float y2 = x * (1.5957691216057308f + 0.071354816222120564f * x * x);
    y2 = fmaxf(fminf(y2, 30.f), -30.f);
    float t = __expf(y2);
    return x * (t / (1.f + t));
}
__device__ __forceinline__ float fexp(float v) {     // e^v, clamped to <= 0
    return __expf(fminf(v, 0.f));
}

// ---------------- packed-weight layout (bf16 elements) ----------------
#define PK_WIN   0        // 64x128,  KB=2
#define PK_M     8192     // 128x128, KB=4
#define PK_WV    24576    // 128x128, KB=4
#define PK_WOUT  40960    // 128x128, KB=4
#define PK_WFF1  57344    // 128x256, KB=4
#define PK_WFF2  90112    // 256x128, KB=8
#define PK_WLIN  122880   // 128x64,  KB=4
#define PK_TOTAL 131072

__global__ __launch_bounds__(256)
void pack_kernel(const float* __restrict__ W_in, const float* __restrict__ W_qk,
                 const float* __restrict__ W_v,  const float* __restrict__ W_out,
                 const float* __restrict__ W_ff1,const float* __restrict__ W_ff2,
                 const float* __restrict__ W_lin, unsigned short* __restrict__ pk)
{
    int i = blockIdx.x * 256 + threadIdx.x;
    if (i >= PK_TOTAL) return;
    const float* src = nullptr; int N = 0, off, KB;
    if      (i < PK_M)    { src = W_in;  N = 128; off = PK_WIN;  KB = 2; }
    else if (i < PK_WV)   {              N = 0;   off = PK_M;    KB = 4; }
    else if (i < PK_WOUT) { src = W_v;   N = 128; off = PK_WV;   KB = 4; }
    else if (i < PK_WFF1) { src = W_out; N = 128; off = PK_WOUT; KB = 4; }
    else if (i < PK_WFF2) { src = W_ff1; N = 256; off = PK_WFF1; KB = 4; }
    else if (i < PK_WLIN) { src = W_ff2; N = 128; off = PK_WFF2; KB = 8; }
    else                  { src = W_lin; N = 64;  off = PK_WLIN; KB = 4; }
    int p = i - off;
    int ei = p & 7, lane = (p >> 3) & 63, rest = p >> 9;
    int kb = rest % KB, ct = rest / KB;
    int k = kb * 32 + ((lane >> 4) << 3) + ei;
    int n = ct * 16 + (lane & 15);
    float v;
    if (off == PK_M) {
        const f32x4_t* wq = (const f32x4_t*)(W_qk + k * 256);
        const f32x4_t* wk = (const f32x4_t*)(W_qk + n * 256 + 128);
        f32x4_t a4 = {0.f, 0.f, 0.f, 0.f};
        #pragma unroll
        for (int d = 0; d < 32; ++d) a4 += wq[d] * wk[d];
        v = (a4[0] + a4[1] + a4[2] + a4[3]) * (1.f / 128.f);
    } else {
        if (off == PK_WIN)  k = (k & 15) * 4 + ((k >> 5) & 1) * 2 + ((k >> 4) & 1);
        if (off == PK_WLIN) n = (n & 15) * 4 + ((n >> 5) & 1) * 2 + ((n >> 4) & 1);
        v = src[k * N + n];
        if (off == PK_WV) v *= 0.088388347648318447f;
    }
    pk[i] = f2b(v);
}

// ---------------- trans LDS pool (32768 B) ----------------
#define OFF_A  8704
#define OFF_B  17408
#define OFF_C  26112
#define OFF_P  30720
#define LDS_SZ 32768

// 512 threads = 8 waves/block; 4 blocks/CU x 8 waves = 32 waves/CU (full TLP).
// Per-wave work halved: each wave owns ONE 16-col tile (ct = wv).
template<int PASS>
__global__ __launch_bounds__(512, 8)
void trans_mfma(const void* __restrict__ src_, unsigned short* __restrict__ dst,
                const unsigned short* __restrict__ pk,
                const float* __restrict__ g1, const float* __restrict__ b1,
                const float* __restrict__ g2, const float* __restrict__ b2)
{
    __shared__ __align__(16) char POOL[LDS_SZ];
    unsigned short* Tb  = (unsigned short*)POOL;              // [32][136]
    unsigned short* xs  = (unsigned short*)(POOL + OFF_A);    // [32][72]
    unsigned short* Tn  = (unsigned short*)(POOL + OFF_A);    // [32][136]
    unsigned short* Ob  = (unsigned short*)(POOL + OFF_A);    // [32][136]
    unsigned short* U   = (unsigned short*)(POOL + OFF_B);    // [32][136]
    unsigned short* Vt  = (unsigned short*)(POOL + OFF_B);    // [128][34]
    unsigned short* FFh = (unsigned short*)(POOL + OFF_B);    // [32][136]
    float*          Ssc = (float*)         (POOL + OFF_C);    // [32][36]
    unsigned short* Pp  = (unsigned short*)(POOL + OFF_P);    // [32][32]

    const int tid  = threadIdx.x;
    const int lane = tid & 63;
    const int wv   = tid >> 6;          // 0..7
    const int lr   = lane & 15;
    const int lg   = lane >> 4;

    const int bid = blockIdx.x;
    const int n = (bid & 7) * 2592 + (bid >> 3);
    const int q = n & 31;
    int r_ = n >> 5;
    const int v_ = r_ % 9; r_ /= 9;
    const int u_ = r_ % 9;
    const int b_ = r_ / 9;
    const int s_ = u_ * 9 + v_;
    const size_t plane = (size_t)(b_ * 16) * 81 + s_;
    const size_t bs_pm = (size_t)(b_ * 81 + s_);

    auto ldA = [&](const unsigned short* buf, int stride, int rt, int kb) -> bf16x8_t {
        return *(const bf16x8_t*)(buf + (rt * 16 + lr) * stride + kb * 32 + lg * 8);
    };
    auto ldB = [&](int base, int KB, int ct, int kb) -> bf16x8_t {
        return *(const bf16x8_t*)(pk + base + (((ct * KB + kb) * 64 + lane) << 3));
    };
    auto stCol = [&](unsigned short* buf, int r0, int col, f32x4_t v) {
        unsigned int u0 = pk2(v[0], v[1]), u1 = pk2(v[2], v[3]);
        buf[(r0 + 0) * 136 + col] = (unsigned short)u0;
        buf[(r0 + 1) * 136 + col] = (unsigned short)(u0 >> 16);
        buf[(r0 + 2) * 136 + col] = (unsigned short)u1;
        buf[(r0 + 3) * 136 + col] = (unsigned short)(u1 >> 16);
    };

    // residual master: two named registers (wave owns cols [16wv,16wv+16))
    f32x4_t t0, t1;
    auto stT = [&](int r, f32x4_t v) {
        stCol(Tb, r * 16 + lg * 4, wv * 16 + lr, v);
    };

    // ---- gather tokens -> xs bf16 [32][72], cin' = ph*32+pw*16+c ----
    if (PASS == 1) {
        const float* srcf = (const float*)src_;
        for (int i = tid; i < 1024; i += 512) {
            const int t = i >> 5, rest = i & 31;
            const int c = rest & 15, ph = rest >> 4;
            float2 f = *(const float2*)(srcf + (plane + (size_t)c * 81) * 4096
                                        + (2 * t + ph) * 64 + 2 * q);
            unsigned int u = pk2(f.x, f.y);
            xs[t * 72 + ph * 32 + c]      = (unsigned short)u;
            xs[t * 72 + ph * 32 + 16 + c] = (unsigned short)(u >> 16);
        }
    } else {
        const unsigned short* srcb = (const unsigned short*)src_;
        const int t = tid >> 4, rest = tid & 15;
        const int ch4 = rest & 3, pw = (rest >> 2) & 1, ph = rest >> 3;
        uint2 v = *(const uint2*)(srcb + ((bs_pm * 64 + (2 * q + ph)) * 64
                                  + (2 * t + pw)) * 16 + ch4 * 4);
        *(uint2*)(xs + t * 72 + ph * 32 + pw * 16 + ch4 * 4) = v;
    }
    __syncthreads();

    // ---- G1: T = xs @ W_in (32x64x128); wave: ct=wv, rt=0,1 ----
    {
        bf16x8_t a00 = ldA(xs, 72, 0, 0), a01 = ldA(xs, 72, 0, 1);
        bf16x8_t a10 = ldA(xs, 72, 1, 0), a11 = ldA(xs, 72, 1, 1);
        bf16x8_t b0 = ldB(PK_WIN, 2, wv, 0), b1 = ldB(PK_WIN, 2, wv, 1);
        const f32x4_t z = {0.f, 0.f, 0.f, 0.f};
        t0 = mfma16(a01, b1, mfma16(a00, b0, z));
        t1 = mfma16(a11, b1, mfma16(a10, b0, z));
        stT(0, t0); stT(1, t1);
    }
    __syncthreads();

    // ---- LN: 16 threads/row, 8 values each ----
    auto layernorm = [&](const float* g, const float* bb) {
        const int row = tid >> 4, sub = tid & 15;
        uint4 w0 = *(const uint4*)(Tb + row * 136 + sub * 8);
        float v[8];
        ub2(w0.x, v[0], v[1]); ub2(w0.y, v[2], v[3]);
        ub2(w0.z, v[4], v[5]); ub2(w0.w, v[6], v[7]);
        float sum = 0.f;
        #pragma unroll
        for (int i = 0; i < 8; ++i) sum += v[i];
        #pragma unroll
        for (int m = 1; m < 16; m <<= 1) sum += __shfl_xor(sum, m, 16);
        const float mean = sum * (1.f / 128.f);
        float var = 0.f;
        #pragma unroll
        for (int i = 0; i < 8; ++i) { float d = v[i] - mean; var += d * d; }
        #pragma unroll
        for (int m = 1; m < 16; m <<= 1) var += __shfl_xor(var, m, 16);
        const float rstd = rsqrtf(var * (1.f / 128.f) + 1e-5f);
        f32x4_t g0 = *(const f32x4_t*)(g + sub * 8),  g1v = *(const f32x4_t*)(g + sub * 8 + 4);
        f32x4_t b0 = *(const f32x4_t*)(bb + sub * 8), b1v = *(const f32x4_t*)(bb + sub * 8 + 4);
        float o[8];
        #pragma unroll
        for (int i = 0; i < 4; ++i) {
            o[i]     = (v[i]     - mean) * rstd * g0[i]  + b0[i];
            o[4 + i] = (v[4 + i] - mean) * rstd * g1v[i] + b1v[i];
        }
        uint4 u0;
        u0.x = pk2(o[0], o[1]); u0.y = pk2(o[2], o[3]);
        u0.z = pk2(o[4], o[5]); u0.w = pk2(o[6], o[7]);
        *(uint4*)(Tn + row * 136 + sub * 8) = u0;
    };

    layernorm(g1, b1);
    __syncthreads();

    // ---- U = Tn @ M (32x128x128); wave: ct=wv, rt=0,1 ----
    {
        bf16x8_t b[4];
        #pragma unroll
        for (int k = 0; k < 4; ++k) b[k] = ldB(PK_M, 4, wv, k);
        #pragma unroll
        for (int r = 0; r < 2; ++r) {
            bf16x8_t a[4];
            #pragma unroll
            for (int k = 0; k < 4; ++k) a[k] = ldA(Tn, 136, r, k);
            f32x4_t acc = {0.f, 0.f, 0.f, 0.f};
            #pragma unroll
            for (int k = 0; k < 4; ++k) acc = mfma16(a[k], b[k], acc);
            stCol(U, r * 16 + lg * 4, wv * 16 + lr, acc);
        }
    }
    __syncthreads();

    // ---- scores: S = U @ Tn^T (32x128x32); 4 tiles on waves 0-3 ----
    if (wv < 4) {
        const int rt = wv & 1, ct = wv >> 1;
        bf16x8_t a[4], b[4];
        #pragma unroll
        for (int k = 0; k < 4; ++k) { a[k] = ldA(U, 136, rt, k); b[k] = ldA(Tn, 136, ct, k); }
        f32x4_t acc = {0.f, 0.f, 0.f, 0.f};
        #pragma unroll
        for (int k = 0; k < 4; ++k) acc = mfma16(a[k], b[k], acc);
        const int col = ct * 16 + lr, r0 = rt * 16 + lg * 4;
        #pragma unroll
        for (int i = 0; i < 4; ++i) Ssc[(r0 + i) * 36 + col] = acc[i];
    }
    __syncthreads();

    // ---- softmax (16 thr/row, 2 vals) -> Pp ; Wv: Vt = (Tb @ Wv*s)^T ----
    {
        const int row = tid >> 4, sub = tid & 15;
        float v0 = Ssc[row * 36 + sub * 2], v1 = Ssc[row * 36 + sub * 2 + 1];
        float mx = fmaxf(v0, v1);
        #pragma unroll
        for (int m = 1; m < 16; m <<= 1) mx = fmaxf(mx, __shfl_xor(mx, m, 16));
        v0 = fexp(v0 - mx); v1 = fexp(v1 - mx);
        float sm = v0 + v1;
        #pragma unroll
        for (int m = 1; m < 16; m <<= 1) sm += __shfl_xor(sm, m, 16);
        const float inv = 1.f / sm;
        *(unsigned int*)(Pp + row * 32 + sub * 2) = pk2(v0 * inv, v1 * inv);
    }
    {
        bf16x8_t b[4];
        #pragma unroll
        for (int k = 0; k < 4; ++k) b[k] = ldB(PK_WV, 4, wv, k);
        #pragma unroll
        for (int r = 0; r < 2; ++r) {
            bf16x8_t a[4];
            #pragma unroll
            for (int k = 0; k < 4; ++k) a[k] = ldA(Tb, 136, r, k);
            f32x4_t acc = {0.f, 0.f, 0.f, 0.f};
            #pragma unroll
            for (int k = 0; k < 4; ++k) acc = mfma16(a[k], b[k], acc);
            const int col = wv * 16 + lr, r0 = r * 16 + lg * 4;
            uint2 vu;
            vu.x = pk2(acc[0], acc[1]);
            vu.y = pk2(acc[2], acc[3]);
            *(uint2*)(Vt + col * 34 + r0) = vu;
        }
    }
    __syncthreads();

    // ---- PV: Ob = P @ V (32x32x128); wave: ct=wv ----
    {
        bf16x8_t aa0 = ldA(Pp, 32, 0, 0), aa1 = ldA(Pp, 32, 1, 0);
        bf16x8_t bb = ldA(Vt, 34, wv, 0);
        const f32x4_t z = {0.f, 0.f, 0.f, 0.f};
        f32x4_t o0 = mfma16(aa0, bb, z), o1 = mfma16(aa1, bb, z);
        const int c0 = wv * 16 + lr;
        stCol(Ob, lg * 4,      c0, o0);
        stCol(Ob, 16 + lg * 4, c0, o1);
    }
    __syncthreads();

    // ---- Wout: t += Ob @ W_out ----
    {
        bf16x8_t b[4];
        #pragma unroll
        for (int k = 0; k < 4; ++k) b[k] = ldB(PK_WOUT, 4, wv, k);
        f32x4_t a0 = {0.f,0.f,0.f,0.f}, a1 = a0;
        {
            bf16x8_t a[4];
            #pragma unroll
            for (int k = 0; k < 4; ++k) a[k] = ldA(Ob, 136, 0, k);
            #pragma unroll
            for (int k = 0; k < 4; ++k) a0 = mfma16(a[k], b[k], a0);
        }
        {
            bf16x8_t a[4];
            #pragma unroll
            for (int k = 0; k < 4; ++k) a[k] = ldA(Ob, 136, 1, k);
            #pragma unroll
            for (int k = 0; k < 4; ++k) a1 = mfma16(a[k], b[k], a1);
        }
        t0 += a0; t1 += a1;
        stT(0, t0); stT(1, t1);
    }
    __syncthreads();

    layernorm(g2, b2);
    __syncthreads();

    // ---- ff: two 128-col halves; ff2 accumulates in named registers ----
    {
        f32x4_t f0 = {0.f,0.f,0.f,0.f}, f1 = f0;
        #pragma unroll
        for (int h = 0; h < 2; ++h) {
            {   // ff1 half: FFh = gelu(Tn @ Wff1[:, h*128:]); src ct = h*8+wv
                bf16x8_t b[4];
                #pragma unroll
                for (int k = 0; k < 4; ++k) b[k] = ldB(PK_WFF1, 4, h * 8 + wv, k);
                #pragma unroll
                for (int r = 0; r < 2; ++r) {
                    bf16x8_t a[4];
                    #pragma unroll
                    for (int k = 0; k < 4; ++k) a[k] = ldA(Tn, 136, r, k);
                    f32x4_t acc = {0.f, 0.f, 0.f, 0.f};
                    #pragma unroll
                    for (int k = 0; k < 4; ++k) acc = mfma16(a[k], b[k], acc);
                    f32x4_t gv;
                    #pragma unroll
                    for (int i = 0; i < 4; ++i) gv[i] = gelu_f(acc[i]);
                    stCol(FFh, r * 16 + lg * 4, wv * 16 + lr, gv);
                }
            }
            __syncthreads();
            {   // ff2 half: f += FFh @ Wff2[h*128:,:]; out ct = wv
                bf16x8_t b[4];
                #pragma unroll
                for (int k = 0; k < 4; ++k) b[k] = ldB(PK_WFF2, 8, wv, h * 4 + k);
                {
                    bf16x8_t a[4];
                    #pragma unroll
                    for (int k = 0; k < 4; ++k) a[k] = ldA(FFh, 136, 0, k);
                    #pragma unroll
                    for (int k = 0; k < 4; ++k) f0 = mfma16(a[k], b[k], f0);
                }
                {
                    bf16x8_t a[4];
                    #pragma unroll
                    for (int k = 0; k < 4; ++k) a[k] = ldA(FFh, 136, 1, k);
                    #pragma unroll
                    for (int k = 0; k < 4; ++k) f1 = mfma16(a[k], b[k], f1);
                }
            }
            __syncthreads();
        }
        t0 += f0; t1 += f1;
        stT(0, t0); stT(1, t1);
    }
    __syncthreads();

    // ---- Wlin: 8 tiles (r, ct) over 8 waves -> scatter pixel-major ----
    {
        const int ct = wv & 3, r = wv >> 2;
        const int ph = ct >> 1, pw = ct & 1;
        bf16x8_t b[4];
        #pragma unroll
        for (int k = 0; k < 4; ++k) b[k] = ldB(PK_WLIN, 4, ct, k);
        bf16x8_t a[4];
        #pragma unroll
        for (int k = 0; k < 4; ++k) a[k] = ldA(Tb, 136, r, k);
        f32x4_t acc = {0.f, 0.f, 0.f, 0.f};
        #pragma unroll
        for (int k = 0; k < 4; ++k) acc = mfma16(a[k], b[k], acc);
        const int r0 = r * 16 + lg * 4;
        unsigned int u0 = pk2(acc[0], acc[1]), u1 = pk2(acc[2], acc[3]);
        unsigned short s4[4] = { (unsigned short)u0, (unsigned short)(u0 >> 16),
                                 (unsigned short)u1, (unsigned short)(u1 >> 16) };
        #pragma unroll
        for (int i = 0; i < 4; ++i) {
            const int t = r0 + i;
            size_t pix;
            if (PASS == 1) pix = (bs_pm * 64 + (2 * t + ph)) * 64 + (2 * q + pw);
            else           pix = (bs_pm * 64 + (2 * q + ph)) * 64 + (2 * t + pw);
            dst[pix * 16 + lr] = s4[i];
        }
    }
}

// ---------------- MFMA conv: 3x3, 16->16 ch, pad 1, leaky 0.2 (R5-verified) ----
template<bool SWAPW, bool ADDSC, bool F32OUT>
__global__ __launch_bounds__(256, 3)
void conv_mfma(const unsigned short* __restrict__ in, void* __restrict__ out_,
               const float* __restrict__ wgt, const float* __restrict__ shortcut)
{
    __shared__ unsigned short tin[18 * 66 * 16];
    __shared__ unsigned short wpk[5 * 64 * 8];

    const int tid = threadIdx.x, lane = tid & 63, wv = tid >> 6;
    const int lr = lane & 15, lg = lane >> 4;
    const int blk = blockIdx.x;
    const int yt = blk & 3, bs = blk >> 2;
    const int s_ = bs % 81, b_ = bs / 81;
    const int y0 = yt * 16;

    for (int i = tid; i < 72; i += 256) {
        const int row = i >> 2, qh = i & 3;
        const int slot = (qh >> 1) ? 65 : 0, half = (qh & 1) * 8;
        *(bf16x8_t*)(tin + (row * 66 + slot) * 16 + half) = bf16x8_t{};
    }
    for (int i = tid; i < 2304; i += 256) {
        const int row = i >> 7, c2 = i & 127, px = c2 >> 1, half = (c2 & 1) * 8;
        const int yg = y0 + row - 1;
        bf16x8_t v{};
        if (yg >= 0 && yg < 64)
            v = *(const bf16x8_t*)(in + ((size_t)(bs * 64 + yg) * 64 + px) * 16 + half);
        *(bf16x8_t*)(tin + (row * 66 + 1 + px) * 16 + half) = v;
    }
    for (int i = tid; i < 2560; i += 256) {
        const int kb = i >> 9, rest = i & 511, ln = rest >> 3, e = rest & 7;
        const int kl = ((ln >> 4) << 3) + e;
        const int tap = kb * 2 + (kl >> 4), ci = kl & 15, co = ln & 15;
        float w = 0.f;
        if (tap < 9) {
            const int tq = SWAPW ? (tap % 3) * 3 + tap / 3 : tap;
            w = wgt[(co * 16 + ci) * 9 + tq];
        }
        wpk[(kb * 64 + ln) * 8 + e] = f2b(w);
    }
    __syncthreads();

    const int xbase = wv * 16;
    for (int y = 0; y < 16; ++y) {
        f32x4_t acc = {0.f, 0.f, 0.f, 0.f};
        #pragma unroll
        for (int kb = 0; kb < 5; ++kb) {
            int tap = kb * 2 + (lg >> 1); tap = tap > 8 ? 8 : tap;
            const int dy = tap / 3, dxo = tap - dy * 3;
            const bf16x8_t a = *(const bf16x8_t*)(tin +
                ((y + dy) * 66 + xbase + lr + dxo) * 16 + (lg & 1) * 8);
            const bf16x8_t b = *(const bf16x8_t*)(wpk + (kb * 64 + lane) * 8);
            acc = mfma16(a, b, acc);
        }
        const int yg = y0 + y;
        const size_t cbase = ((size_t)(b_ * 16 + lr) * 81 + s_) * 4096
                           + (size_t)yg * 64 + xbase + lg * 4;
        if (F32OUT) {
            float* outf = (float*)out_;
            f32x4_t r;
            if (ADDSC) {
                f32x4_t sc = *(const f32x4_t*)(shortcut + cbase);
                #pragma unroll
                for (int i = 0; i < 4; ++i) r[i] = fmaxf(acc[i], 0.2f * acc[i]) + sc[i];
            } else {
                #pragma unroll
                for (int i = 0; i < 4; ++i) r[i] = fmaxf(acc[i], 0.2f * acc[i]);
            }
            *(f32x4_t*)(outf + cbase) = r;
        } else {
            unsigned short* outb = (unsigned short*)out_;
            const size_t pbase = ((size_t)(bs * 64 + yg) * 64 + xbase + lg * 4) * 16 + lr;
            f32x4_t sc = {0.f, 0.f, 0.f, 0.f};
            if (ADDSC) sc = *(const f32x4_t*)(shortcut + cbase);
            f32x4_t r;
            #pragma unroll
            for (int i = 0; i < 4; ++i) r[i] = fmaxf(acc[i], 0.2f * acc[i]) + sc[i];
            unsigned int u0 = pk2(r[0], r[1]), u1 = pk2(r[2], r[3]);
            outb[pbase + 0]  = (unsigned short)u0;
            outb[pbase + 16] = (unsigned short)(u0 >> 16);
            outb[pbase + 32] = (unsigned short)u1;
            outb[pbase + 48] = (unsigned short)(u1 >> 16);
        }
    }
}

extern "C" void kernel_launch(void* const* d_in, const int* in_sizes, int n_in,
                              void* d_out, int out_size, void* d_ws, size_t ws_size,
                              hipStream_t stream)
{
    const float* buffer = (const float*)d_in[0];
    const float* W_in   = (const float*)d_in[1];
    const float* ln1_g  = (const float*)d_in[2];
    const float* ln1_b  = (const float*)d_in[3];
    const float* W_qk   = (const float*)d_in[4];
    const float* W_v    = (const float*)d_in[5];
    const float* W_out  = (const float*)d_in[6];
    const float* ln2_g  = (const float*)d_in[7];
    const float* ln2_b  = (const float*)d_in[8];
    const float* W_ff1  = (const float*)d_in[9];
    const float* W_ff2  = (const float*)d_in[10];
    const float* W_lin  = (const float*)d_in[11];
    const float* cw1    = (const float*)d_in[12];
    const float* cw2    = (const float*)d_in[13];
    const float* cw3    = (const float*)d_in[14];

    unsigned short* A   = (unsigned short*)d_ws;
    unsigned short* pkw = (unsigned short*)((char*)d_ws + 84934656);
    unsigned short* B   = (unsigned short*)d_out;

    const dim3 blk256(256), blk512(512);
    const dim3 tgrid(20736);
    const dim3 cgrid(648 * 4);

    pack_kernel<<<dim3(512), blk256, 0, stream>>>(W_in, W_qk, W_v, W_out, W_ff1, W_ff2, W_lin, pkw);

    // ---- pass 1 ----
    trans_mfma<1><<<tgrid, blk512, 0, stream>>>(buffer, A, pkw, ln1_g, ln1_b, ln2_g, ln2_b);
    conv_mfma<false, false, false><<<cgrid, blk256, 0, stream>>>(A, B, cw1, nullptr);
    conv_mfma<false, false, false><<<cgrid, blk256, 0, stream>>>(B, A, cw2, nullptr);
    conv_mfma<false, true,  false><<<cgrid, blk256, 0, stream>>>(A, B, cw3, buffer);   // x1 bf16 pm -> B

    // ---- pass 2 ((h,w) order kept; conv taps transposed) ----
    trans_mfma<2><<<tgrid, blk512, 0, stream>>>(B, A, pkw, ln1_g, ln1_b, ln2_g, ln2_b);
    conv_mfma<true, false, false><<<cgrid, blk256, 0, stream>>>(A, B, cw1, nullptr);
    conv_mfma<true, false, false><<<cgrid, blk256, 0, stream>>>(B, A, cw2, nullptr);
    conv_mfma<true, true,  true ><<<cgrid, blk256, 0, stream>>>(A, d_out, cw3, buffer); // final fp32
}

// Round 16
// 1123.697 us; speedup vs baseline: 1.1321x; 1.1321x over previous
//
#include <hip/hip_runtime.h>
#include <hip/hip_bf16.h>
#include <cmath>

typedef float  f32x4_t  __attribute__((ext_vector_type(4)));
typedef short  bf16x8_t __attribute__((ext_vector_type(8)));

// bf16 converts via HIP header intrinsics; memcpy extraction (bit_cast illegal
// on non-trivially-copyable __hip_bfloat16x in ROCm 7.2).
__device__ __forceinline__ unsigned short f2b(float f) {
    __hip_bfloat16 h = __float2bfloat16(f);
    unsigned short r;
    __builtin_memcpy(&r, &h, 2);
    return r;
}
__device__ __forceinline__ unsigned int pk2(float lo, float hi) {
    __hip_bfloat162 h = __float22bfloat162_rn(float2{lo, hi});
    unsigned int r;
    __builtin_memcpy(&r, &h, 4);
    return r;
}
__device__ __forceinline__ void ub2(unsigned int u, float& lo, float& hi) {
    lo = __builtin_bit_cast(float, u << 16);
    hi = __builtin_bit_cast(float, u & 0xffff0000u);
}
__device__ __forceinline__ f32x4_t mfma16(bf16x8_t a, bf16x8_t b, f32x4_t c) {
    return __builtin_amdgcn_mfma_f32_16x16x32_bf16(a, b, c, 0, 0, 0);
}
__device__ __forceinline__ float gelu_f(float x) {   // NaN-safe tanh-gelu
    float y2 = x * (1.5957691216057308f + 0.071354816222120564f * x * x);
    y2 = fmaxf(fminf(y2, 30.f), -30.f);
    float t = __expf(y2);                            // fast v_exp_f32 path
    return x * (t / (1.f + t));
}
__device__ __forceinline__ float fexp(float v) {     // e^v, clamped to <= 0
    return __expf(fminf(v, 0.f));
}

// ---------------- packed-weight layout (bf16 elements) ----------------
#define PK_WIN   0        // 64x128,  KB=2
#define PK_M     8192     // 128x128, KB=4
#define PK_WV    24576    // 128x128, KB=4
#define PK_WOUT  40960    // 128x128, KB=4
#define PK_WFF1  57344    // 128x256, KB=4
#define PK_WFF2  90112    // 256x128, KB=8
#define PK_WLIN  122880   // 128x64,  KB=4
#define PK_TOTAL 131072

__global__ __launch_bounds__(256)
void pack_kernel(const float* __restrict__ W_in, const float* __restrict__ W_qk,
                 const float* __restrict__ W_v,  const float* __restrict__ W_out,
                 const float* __restrict__ W_ff1,const float* __restrict__ W_ff2,
                 const float* __restrict__ W_lin, unsigned short* __restrict__ pk)
{
    int i = blockIdx.x * 256 + threadIdx.x;
    if (i >= PK_TOTAL) return;
    const float* src = nullptr; int N = 0, off, KB;
    if      (i < PK_M)    { src = W_in;  N = 128; off = PK_WIN;  KB = 2; }
    else if (i < PK_WV)   {              N = 0;   off = PK_M;    KB = 4; }
    else if (i < PK_WOUT) { src = W_v;   N = 128; off = PK_WV;   KB = 4; }
    else if (i < PK_WFF1) { src = W_out; N = 128; off = PK_WOUT; KB = 4; }
    else if (i < PK_WFF2) { src = W_ff1; N = 256; off = PK_WFF1; KB = 4; }
    else if (i < PK_WLIN) { src = W_ff2; N = 128; off = PK_WFF2; KB = 8; }
    else                  { src = W_lin; N = 64;  off = PK_WLIN; KB = 4; }
    int p = i - off;
    int ei = p & 7, lane = (p >> 3) & 63, rest = p >> 9;
    int kb = rest % KB, ct = rest / KB;
    int k = kb * 32 + ((lane >> 4) << 3) + ei;
    int n = ct * 16 + (lane & 15);
    float v;
    if (off == PK_M) {
        const f32x4_t* wq = (const f32x4_t*)(W_qk + k * 256);
        const f32x4_t* wk = (const f32x4_t*)(W_qk + n * 256 + 128);
        f32x4_t a4 = {0.f, 0.f, 0.f, 0.f};
        #pragma unroll
        for (int d = 0; d < 32; ++d) a4 += wq[d] * wk[d];
        v = (a4[0] + a4[1] + a4[2] + a4[3]) * (1.f / 128.f);
    } else {
        if (off == PK_WIN)  k = (k & 15) * 4 + ((k >> 5) & 1) * 2 + ((k >> 4) & 1);
        if (off == PK_WLIN) n = (n & 15) * 4 + ((n >> 5) & 1) * 2 + ((n >> 4) & 1);
        v = src[k * N + n];
        if (off == PK_WV) v *= 0.088388347648318447f;
    }
    pk[i] = f2b(v);
}

// ---------------- trans LDS pool (32768 B) ----------------
#define OFF_A  8704
#define OFF_B  17408
#define OFF_C  26112
#define OFF_P  30720
#define LDS_SZ 32768

// (256,4): the measured VGPR/occupancy equilibrium (best = ~1124 us total).
// All four escape axes measured as spill-bound: R7/R11 (forced blocks/CU),
// R12 (register prefetch), R14 (8-wave blocks, occupancy 90% but VGPR 32).
template<int PASS>
__global__ __launch_bounds__(256, 4)
void trans_mfma(const void* __restrict__ src_, unsigned short* __restrict__ dst,
                const unsigned short* __restrict__ pk,
                const float* __restrict__ g1, const float* __restrict__ b1,
                const float* __restrict__ g2, const float* __restrict__ b2)
{
    __shared__ __align__(16) char POOL[LDS_SZ];
    unsigned short* Tb  = (unsigned short*)POOL;              // [32][136]
    unsigned short* xs  = (unsigned short*)(POOL + OFF_A);    // [32][72]
    unsigned short* Tn  = (unsigned short*)(POOL + OFF_A);    // [32][136]
    unsigned short* Ob  = (unsigned short*)(POOL + OFF_A);    // [32][136]
    unsigned short* U   = (unsigned short*)(POOL + OFF_B);    // [32][136]
    unsigned short* Vt  = (unsigned short*)(POOL + OFF_B);    // [128][34]
    unsigned short* FFh = (unsigned short*)(POOL + OFF_B);    // [32][136]
    float*          Ssc = (float*)         (POOL + OFF_C);    // [32][36]
    unsigned short* Pp  = (unsigned short*)(POOL + OFF_P);    // [32][32]

    const int tid  = threadIdx.x;
    const int lane = tid & 63;
    const int wv   = tid >> 6;
    const int lr   = lane & 15;
    const int lg   = lane >> 4;

    const int bid = blockIdx.x;
    const int n = (bid & 7) * 2592 + (bid >> 3);
    const int q = n & 31;
    int r_ = n >> 5;
    const int v_ = r_ % 9; r_ /= 9;
    const int u_ = r_ % 9;
    const int b_ = r_ / 9;
    const int s_ = u_ * 9 + v_;
    const size_t plane = (size_t)(b_ * 16) * 81 + s_;
    const size_t bs_pm = (size_t)(b_ * 81 + s_);

    auto ldA = [&](const unsigned short* buf, int stride, int rt, int kb) -> bf16x8_t {
        return *(const bf16x8_t*)(buf + (rt * 16 + lr) * stride + kb * 32 + lg * 8);
    };
    auto ldB = [&](int base, int KB, int ct, int kb) -> bf16x8_t {
        return *(const bf16x8_t*)(pk + base + (((ct * KB + kb) * 64 + lane) << 3));
    };
    // pair-convert column store: 4 values -> 2 pk2 + 2 shifts
    auto stCol = [&](unsigned short* buf, int r0, int col, f32x4_t v) {
        unsigned int u0 = pk2(v[0], v[1]), u1 = pk2(v[2], v[3]);
        buf[(r0 + 0) * 136 + col] = (unsigned short)u0;
        buf[(r0 + 1) * 136 + col] = (unsigned short)(u0 >> 16);
        buf[(r0 + 2) * 136 + col] = (unsigned short)u1;
        buf[(r0 + 3) * 136 + col] = (unsigned short)(u1 >> 16);
    };

    // residual master: four named registers (wave owns cols [32wv,32wv+32))
    f32x4_t t00, t01, t10, t11;
    auto stT = [&](int r, int c, f32x4_t v) {
        stCol(Tb, r * 16 + lg * 4, (2 * wv + c) * 16 + lr, v);
    };

    // ---- gather tokens -> xs bf16 [32][72], cin' = ph*32+pw*16+c ----
    if (PASS == 1) {
        const float* srcf = (const float*)src_;
        for (int i = tid; i < 1024; i += 256) {
            const int t = i >> 5, rest = i & 31;
            const int c = rest & 15, ph = rest >> 4;
            float2 f = *(const float2*)(srcf + (plane + (size_t)c * 81) * 4096
                                        + (2 * t + ph) * 64 + 2 * q);
            unsigned int u = pk2(f.x, f.y);
            xs[t * 72 + ph * 32 + c]      = (unsigned short)u;
            xs[t * 72 + ph * 32 + 16 + c] = (unsigned short)(u >> 16);
        }
    } else {
        const unsigned short* srcb = (const unsigned short*)src_;
        const int t = tid >> 3, rest = tid & 7;
        const int ch = rest & 1, pw = (rest >> 1) & 1, ph = rest >> 2;
        bf16x8_t v = *(const bf16x8_t*)(srcb + ((bs_pm * 64 + (2 * q + ph)) * 64
                                        + (2 * t + pw)) * 16 + ch * 8);
        *(bf16x8_t*)(xs + t * 72 + ph * 32 + pw * 16 + ch * 8) = v;
    }
    __syncthreads();

    // ---- G1: T = xs @ W_in (32x64x128) -> t00..t11 + Tb ----
    {
        const int ct0 = 2 * wv;
        bf16x8_t a00 = ldA(xs, 72, 0, 0), a01 = ldA(xs, 72, 0, 1);
        bf16x8_t a10 = ldA(xs, 72, 1, 0), a11 = ldA(xs, 72, 1, 1);
        bf16x8_t b00 = ldB(PK_WIN, 2, ct0, 0),     b01 = ldB(PK_WIN, 2, ct0, 1);
        bf16x8_t b10 = ldB(PK_WIN, 2, ct0 + 1, 0), b11 = ldB(PK_WIN, 2, ct0 + 1, 1);
        const f32x4_t z = {0.f, 0.f, 0.f, 0.f};
        t00 = mfma16(a01, b01, mfma16(a00, b00, z));
        t01 = mfma16(a01, b11, mfma16(a00, b10, z));
        t10 = mfma16(a11, b01, mfma16(a10, b00, z));
        t11 = mfma16(a11, b11, mfma16(a10, b10, z));
        stT(0, 0, t00); stT(0, 1, t01); stT(1, 0, t10); stT(1, 1, t11);
    }
    __syncthreads();

    // ---- LN helper: reads Tb (bf16), writes Tn (bf16); vector g/b loads ----
    auto layernorm = [&](const float* g, const float* bb) {
        const int row = tid >> 3, sub = tid & 7;
        const unsigned short* tr = Tb + row * 136 + sub * 16;
        uint4 w0 = *(const uint4*)tr, w1 = *(const uint4*)(tr + 8);
        float v[16];
        ub2(w0.x, v[0], v[1]);   ub2(w0.y, v[2], v[3]);
        ub2(w0.z, v[4], v[5]);   ub2(w0.w, v[6], v[7]);
        ub2(w1.x, v[8], v[9]);   ub2(w1.y, v[10], v[11]);
        ub2(w1.z, v[12], v[13]); ub2(w1.w, v[14], v[15]);
        float sum = 0.f;
        #pragma unroll
        for (int i = 0; i < 16; ++i) sum += v[i];
        #pragma unroll
        for (int m = 1; m < 8; m <<= 1) sum += __shfl_xor(sum, m, 8);
        const float mean = sum * (1.f / 128.f);
        float var = 0.f;
        #pragma unroll
        for (int i = 0; i < 16; ++i) { float d = v[i] - mean; var += d * d; }
        #pragma unroll
        for (int m = 1; m < 8; m <<= 1) var += __shfl_xor(var, m, 8);
        const float rstd = rsqrtf(var * (1.f / 128.f) + 1e-5f);
        const f32x4_t* g4 = (const f32x4_t*)(g + sub * 16);
        const f32x4_t* b4 = (const f32x4_t*)(bb + sub * 16);
        float o[16];
        #pragma unroll
        for (int j = 0; j < 4; ++j) {
            f32x4_t gg = g4[j], bbv = b4[j];
            #pragma unroll
            for (int i = 0; i < 4; ++i) o[j * 4 + i] = (v[j * 4 + i] - mean) * rstd * gg[i] + bbv[i];
        }
        uint4 u0, u1;
        u0.x = pk2(o[0],o[1]);   u0.y = pk2(o[2],o[3]);
        u0.z = pk2(o[4],o[5]);   u0.w = pk2(o[6],o[7]);
        u1.x = pk2(o[8],o[9]);   u1.y = pk2(o[10],o[11]);
        u1.z = pk2(o[12],o[13]); u1.w = pk2(o[14],o[15]);
        *(uint4*)(Tn + row * 136 + sub * 16)     = u0;
        *(uint4*)(Tn + row * 136 + sub * 16 + 8) = u1;
    };

    layernorm(g1, b1);
    __syncthreads();

    // ---- U = Tn @ M (32x128x128) ----
    {
        const int ct0 = 2 * wv;
        bf16x8_t a[2][4], b[2][4];
        #pragma unroll
        for (int r = 0; r < 2; ++r) for (int k = 0; k < 4; ++k) a[r][k] = ldA(Tn, 136, r, k);
        #pragma unroll
        for (int c = 0; c < 2; ++c) for (int k = 0; k < 4; ++k) b[c][k] = ldB(PK_M, 4, ct0 + c, k);
        #pragma unroll
        for (int r = 0; r < 2; ++r)
        #pragma unroll
        for (int c = 0; c < 2; ++c) {
            f32x4_t acc = {0.f, 0.f, 0.f, 0.f};
            #pragma unroll
            for (int k = 0; k < 4; ++k) acc = mfma16(a[r][k], b[c][k], acc);
            stCol(U, r * 16 + lg * 4, (ct0 + c) * 16 + lr, acc);
        }
    }
    __syncthreads();

    // ---- scores: S = U @ Tn^T (32x128x32) ----
    {
        const int rt = wv & 1, ct = wv >> 1;
        bf16x8_t a[4], b[4];
        #pragma unroll
        for (int k = 0; k < 4; ++k) { a[k] = ldA(U, 136, rt, k); b[k] = ldA(Tn, 136, ct, k); }
        f32x4_t acc = {0.f, 0.f, 0.f, 0.f};
        #pragma unroll
        for (int k = 0; k < 4; ++k) acc = mfma16(a[k], b[k], acc);
        const int col = ct * 16 + lr, r0 = rt * 16 + lg * 4;
        #pragma unroll
        for (int i = 0; i < 4; ++i) Ssc[(r0 + i) * 36 + col] = acc[i];
    }
    __syncthreads();

    // ---- softmax -> Pp ; Wv: Vt = (Tb @ Wv*scale)^T ----
    {
        const int row = tid >> 3, sub = tid & 7;
        float v4[4]; float mx = -1e30f;
        #pragma unroll
        for (int i = 0; i < 4; ++i) { v4[i] = Ssc[row * 36 + sub * 4 + i]; mx = fmaxf(mx, v4[i]); }
        #pragma unroll
        for (int m = 1; m < 8; m <<= 1) mx = fmaxf(mx, __shfl_xor(mx, m, 8));
        float sm = 0.f;
        #pragma unroll
        for (int i = 0; i < 4; ++i) { v4[i] = fexp(v4[i] - mx); sm += v4[i]; }
        #pragma unroll
        for (int m = 1; m < 8; m <<= 1) sm += __shfl_xor(sm, m, 8);
        const float inv = 1.f / sm;
        uint2 pu;
        pu.x = pk2(v4[0] * inv, v4[1] * inv);
        pu.y = pk2(v4[2] * inv, v4[3] * inv);
        *(uint2*)(Pp + row * 32 + sub * 4) = pu;
    }
    {
        const int ct0 = 2 * wv;
        bf16x8_t b[2][4];
        #pragma unroll
        for (int c = 0; c < 2; ++c) for (int k = 0; k < 4; ++k) b[c][k] = ldB(PK_WV, 4, ct0 + c, k);
        #pragma unroll
        for (int r = 0; r < 2; ++r) {
            bf16x8_t a[4];
            #pragma unroll
            for (int k = 0; k < 4; ++k) a[k] = ldA(Tb, 136, r, k);
            #pragma unroll
            for (int c = 0; c < 2; ++c) {
                f32x4_t acc = {0.f, 0.f, 0.f, 0.f};
                #pragma unroll
                for (int k = 0; k < 4; ++k) acc = mfma16(a[k], b[c][k], acc);
                const int col = (ct0 + c) * 16 + lr, r0 = r * 16 + lg * 4;
                uint2 vu;
                vu.x = pk2(acc[0], acc[1]);
                vu.y = pk2(acc[2], acc[3]);
                *(uint2*)(Vt + col * 34 + r0) = vu;
            }
        }
    }
    __syncthreads();

    // ---- PV: Ob = P @ V (32x32x128) ----
    {
        const int ct0 = 2 * wv;
        bf16x8_t aa0 = ldA(Pp, 32, 0, 0), aa1 = ldA(Pp, 32, 1, 0);
        bf16x8_t bb0 = ldA(Vt, 34, ct0, 0), bb1 = ldA(Vt, 34, ct0 + 1, 0);
        const f32x4_t z = {0.f, 0.f, 0.f, 0.f};
        f32x4_t o00 = mfma16(aa0, bb0, z), o01 = mfma16(aa0, bb1, z);
        f32x4_t o10 = mfma16(aa1, bb0, z), o11 = mfma16(aa1, bb1, z);
        const int c0 = ct0 * 16 + lr, c1 = (ct0 + 1) * 16 + lr;
        stCol(Ob, lg * 4,      c0, o00);
        stCol(Ob, lg * 4,      c1, o01);
        stCol(Ob, 16 + lg * 4, c0, o10);
        stCol(Ob, 16 + lg * 4, c1, o11);
    }
    __syncthreads();

    // ---- Wout: t += Ob @ W_out; refresh Tb ----
    {
        const int ct0 = 2 * wv;
        bf16x8_t a[2][4], b[2][4];
        #pragma unroll
        for (int r = 0; r < 2; ++r) for (int k = 0; k < 4; ++k) a[r][k] = ldA(Ob, 136, r, k);
        #pragma unroll
        for (int c = 0; c < 2; ++c) for (int k = 0; k < 4; ++k) b[c][k] = ldB(PK_WOUT, 4, ct0 + c, k);
        f32x4_t a00 = {0.f,0.f,0.f,0.f}, a01 = a00, a10 = a00, a11 = a00;
        #pragma unroll
        for (int k = 0; k < 4; ++k) {
            a00 = mfma16(a[0][k], b[0][k], a00);
            a01 = mfma16(a[0][k], b[1][k], a01);
            a10 = mfma16(a[1][k], b[0][k], a10);
            a11 = mfma16(a[1][k], b[1][k], a11);
        }
        t00 += a00; t01 += a01; t10 += a10; t11 += a11;
        stT(0, 0, t00); stT(0, 1, t01); stT(1, 0, t10); stT(1, 1, t11);
    }
    __syncthreads();

    layernorm(g2, b2);
    __syncthreads();

    // ---- ff: two 128-col halves; ff2 accumulates in named registers ----
    {
        const int ct0 = 2 * wv;
        f32x4_t f00 = {0.f,0.f,0.f,0.f}, f01 = f00, f10 = f00, f11 = f00;
        #pragma unroll
        for (int h = 0; h < 2; ++h) {
            {   // ff1 half: FFh = gelu(Tn @ Wff1[:, h*128:])
                bf16x8_t a[2][4], b[2][4];
                #pragma unroll
                for (int r = 0; r < 2; ++r) for (int k = 0; k < 4; ++k) a[r][k] = ldA(Tn, 136, r, k);
                const int cth = h * 8 + ct0;
                #pragma unroll
                for (int c = 0; c < 2; ++c) for (int k = 0; k < 4; ++k) b[c][k] = ldB(PK_WFF1, 4, cth + c, k);
                #pragma unroll
                for (int r = 0; r < 2; ++r)
                #pragma unroll
                for (int c = 0; c < 2; ++c) {
                    f32x4_t acc = {0.f, 0.f, 0.f, 0.f};
                    #pragma unroll
                    for (int k = 0; k < 4; ++k) acc = mfma16(a[r][k], b[c][k], acc);
                    f32x4_t gv;
                    #pragma unroll
                    for (int i = 0; i < 4; ++i) gv[i] = gelu_f(acc[i]);
                    stCol(FFh, r * 16 + lg * 4, (ct0 + c) * 16 + lr, gv);
                }
            }
            __syncthreads();
            {   // ff2 half: f += FFh @ Wff2[h*128:,:]
                bf16x8_t a[2][4], b[2][4];
                #pragma unroll
                for (int r = 0; r < 2; ++r) for (int k = 0; k < 4; ++k) a[r][k] = ldA(FFh, 136, r, k);
                #pragma unroll
                for (int c = 0; c < 2; ++c) for (int k = 0; k < 4; ++k) b[c][k] = ldB(PK_WFF2, 8, ct0 + c, h * 4 + k);
                #pragma unroll
                for (int k = 0; k < 4; ++k) {
                    f00 = mfma16(a[0][k], b[0][k], f00);
                    f01 = mfma16(a[0][k], b[1][k], f01);
                    f10 = mfma16(a[1][k], b[0][k], f10);
                    f11 = mfma16(a[1][k], b[1][k], f11);
                }
            }
            __syncthreads();
        }
        t00 += f00; t01 += f01; t10 += f10; t11 += f11;
        stT(0, 0, t00); stT(0, 1, t01); stT(1, 0, t10); stT(1, 1, t11);
    }
    __syncthreads();

    // ---- Wlin: Y = Tb @ W_lin -> scatter pixel-major bf16 (cin' cols) ----
    {
        const int ct = wv;
        const int ph = ct >> 1, pw = ct & 1;
        bf16x8_t b[4];
        #pragma unroll
        for (int k = 0; k < 4; ++k) b[k] = ldB(PK_WLIN, 4, ct, k);
        #pragma unroll
        for (int r = 0; r < 2; ++r) {
            bf16x8_t a[4];
            #pragma unroll
            for (int k = 0; k < 4; ++k) a[k] = ldA(Tb, 136, r, k);
            f32x4_t acc = {0.f, 0.f, 0.f, 0.f};
            #pragma unroll
            for (int k = 0; k < 4; ++k) acc = mfma16(a[k], b[k], acc);
            const int r0 = r * 16 + lg * 4;
            unsigned int u0 = pk2(acc[0], acc[1]), u1 = pk2(acc[2], acc[3]);
            unsigned short s4[4] = { (unsigned short)u0, (unsigned short)(u0 >> 16),
                                     (unsigned short)u1, (unsigned short)(u1 >> 16) };
            #pragma unroll
            for (int i = 0; i < 4; ++i) {
                const int t = r0 + i;
                size_t pix;
                if (PASS == 1) pix = (bs_pm * 64 + (2 * t + ph)) * 64 + (2 * q + pw);
                else           pix = (bs_pm * 64 + (2 * q + ph)) * 64 + (2 * t + pw);
                dst[pix * 16 + lr] = s4[i];
            }
        }
    }
}

// ---------------- MFMA conv: 3x3, 16->16 ch, pad 1, leaky 0.2 (R5-verified) ----
template<bool SWAPW, bool ADDSC, bool F32OUT>
__global__ __launch_bounds__(256, 3)
void conv_mfma(const unsigned short* __restrict__ in, void* __restrict__ out_,
               const float* __restrict__ wgt, const float* __restrict__ shortcut)
{
    __shared__ unsigned short tin[18 * 66 * 16];
    __shared__ unsigned short wpk[5 * 64 * 8];

    const int tid = threadIdx.x, lane = tid & 63, wv = tid >> 6;
    const int lr = lane & 15, lg = lane >> 4;
    const int blk = blockIdx.x;
    const int yt = blk & 3, bs = blk >> 2;
    const int s_ = bs % 81, b_ = bs / 81;
    const int y0 = yt * 16;

    for (int i = tid; i < 72; i += 256) {
        const int row = i >> 2, qh = i & 3;
        const int slot = (qh >> 1) ? 65 : 0, half = (qh & 1) * 8;
        *(bf16x8_t*)(tin + (row * 66 + slot) * 16 + half) = bf16x8_t{};
    }
    for (int i = tid; i < 2304; i += 256) {
        const int row = i >> 7, c2 = i & 127, px = c2 >> 1, half = (c2 & 1) * 8;
        const int yg = y0 + row - 1;
        bf16x8_t v{};
        if (yg >= 0 && yg < 64)
            v = *(const bf16x8_t*)(in + ((size_t)(bs * 64 + yg) * 64 + px) * 16 + half);
        *(bf16x8_t*)(tin + (row * 66 + 1 + px) * 16 + half) = v;
    }
    for (int i = tid; i < 2560; i += 256) {
        const int kb = i >> 9, rest = i & 511, ln = rest >> 3, e = rest & 7;
        const int kl = ((ln >> 4) << 3) + e;
        const int tap = kb * 2 + (kl >> 4), ci = kl & 15, co = ln & 15;
        float w = 0.f;
        if (tap < 9) {
            const int tq = SWAPW ? (tap % 3) * 3 + tap / 3 : tap;
            w = wgt[(co * 16 + ci) * 9 + tq];
        }
        wpk[(kb * 64 + ln) * 8 + e] = f2b(w);
    }
    __syncthreads();

    const int xbase = wv * 16;
    for (int y = 0; y < 16; ++y) {
        f32x4_t acc = {0.f, 0.f, 0.f, 0.f};
        #pragma unroll
        for (int kb = 0; kb < 5; ++kb) {
            int tap = kb * 2 + (lg >> 1); tap = tap > 8 ? 8 : tap;
            const int dy = tap / 3, dxo = tap - dy * 3;
            const bf16x8_t a = *(const bf16x8_t*)(tin +
                ((y + dy) * 66 + xbase + lr + dxo) * 16 + (lg & 1) * 8);
            const bf16x8_t b = *(const bf16x8_t*)(wpk + (kb * 64 + lane) * 8);
            acc = mfma16(a, b, acc);
        }
        const int yg = y0 + y;
        const size_t cbase = ((size_t)(b_ * 16 + lr) * 81 + s_) * 4096
                           + (size_t)yg * 64 + xbase + lg * 4;
        if (F32OUT) {
            float* outf = (float*)out_;
            f32x4_t r;
            if (ADDSC) {
                f32x4_t sc = *(const f32x4_t*)(shortcut + cbase);
                #pragma unroll
                for (int i = 0; i < 4; ++i) r[i] = fmaxf(acc[i], 0.2f * acc[i]) + sc[i];
            } else {
                #pragma unroll
                for (int i = 0; i < 4; ++i) r[i] = fmaxf(acc[i], 0.2f * acc[i]);
            }
            *(f32x4_t*)(outf + cbase) = r;
        } else {
            unsigned short* outb = (unsigned short*)out_;
            const size_t pbase = ((size_t)(bs * 64 + yg) * 64 + xbase + lg * 4) * 16 + lr;
            f32x4_t sc = {0.f, 0.f, 0.f, 0.f};
            if (ADDSC) sc = *(const f32x4_t*)(shortcut + cbase);
            f32x4_t r;
            #pragma unroll
            for (int i = 0; i < 4; ++i) r[i] = fmaxf(acc[i], 0.2f * acc[i]) + sc[i];
            unsigned int u0 = pk2(r[0], r[1]), u1 = pk2(r[2], r[3]);
            outb[pbase + 0]  = (unsigned short)u0;
            outb[pbase + 16] = (unsigned short)(u0 >> 16);
            outb[pbase + 32] = (unsigned short)u1;
            outb[pbase + 48] = (unsigned short)(u1 >> 16);
        }
    }
}

extern "C" void kernel_launch(void* const* d_in, const int* in_sizes, int n_in,
                              void* d_out, int out_size, void* d_ws, size_t ws_size,
                              hipStream_t stream)
{
    const float* buffer = (const float*)d_in[0];
    const float* W_in   = (const float*)d_in[1];
    const float* ln1_g  = (const float*)d_in[2];
    const float* ln1_b  = (const float*)d_in[3];
    const float* W_qk   = (const float*)d_in[4];
    const float* W_v    = (const float*)d_in[5];
    const float* W_out  = (const float*)d_in[6];
    const float* ln2_g  = (const float*)d_in[7];
    const float* ln2_b  = (const float*)d_in[8];
    const float* W_ff1  = (const float*)d_in[9];
    const float* W_ff2  = (const float*)d_in[10];
    const float* W_lin  = (const float*)d_in[11];
    const float* cw1    = (const float*)d_in[12];
    const float* cw2    = (const float*)d_in[13];
    const float* cw3    = (const float*)d_in[14];

    unsigned short* A   = (unsigned short*)d_ws;
    unsigned short* pkw = (unsigned short*)((char*)d_ws + 84934656);
    unsigned short* B   = (unsigned short*)d_out;

    const dim3 blk256(256);
    const dim3 tgrid(20736);
    const dim3 cgrid(648 * 4);

    pack_kernel<<<dim3(512), blk256, 0, stream>>>(W_in, W_qk, W_v, W_out, W_ff1, W_ff2, W_lin, pkw);

    // ---- pass 1 ----
    trans_mfma<1><<<tgrid, blk256, 0, stream>>>(buffer, A, pkw, ln1_g, ln1_b, ln2_g, ln2_b);
    conv_mfma<false, false, false><<<cgrid, blk256, 0, stream>>>(A, B, cw1, nullptr);
    conv_mfma<false, false, false><<<cgrid, blk256, 0, stream>>>(B, A, cw2, nullptr);
    conv_mfma<false, true,  false><<<cgrid, blk256, 0, stream>>>(A, B, cw3, buffer);   // x1 bf16 pm -> B

    // ---- pass 2 ((h,w) order kept; conv taps transposed) ----
    trans_mfma<2><<<tgrid, blk256, 0, stream>>>(B, A, pkw, ln1_g, ln1_b, ln2_g, ln2_b);
    conv_mfma<true, false, false><<<cgrid, blk256, 0, stream>>>(A, B, cw1, nullptr);
    conv_mfma<true, false, false><<<cgrid, blk256, 0, stream>>>(B, A, cw2, nullptr);
    conv_mfma<true, true,  true ><<<cgrid, blk256, 0, stream>>>(A, d_out, cw3, buffer); // final fp32
}